// Round 3
// baseline (1515.752 us; speedup 1.0000x reference)
//
#include <hip/hip_runtime.h>
#include <hip/hip_bf16.h>

typedef __attribute__((ext_vector_type(8))) short bf16x8;
typedef __attribute__((ext_vector_type(4))) float f32x4;

#define INV_SQRT_2F 0.70710678118654752440f

__device__ __forceinline__ short f2bf(float f) {
  union { float f; unsigned u; } v; v.f = f;
  unsigned r = v.u + 0x7fffu + ((v.u >> 16) & 1u);   // round-to-nearest-even
  return (short)(r >> 16);
}

// ---------------------------------------------------------------------------
// Edge kernel: acc[idx_atom[e]][j] += m[e][j] * (basis_rad[e,:] . W_rbf[:,j])
// 64 edges per block, 256 threads, 2 columns (of 512) per thread.
// W_rbf columns live in registers; basis tile staged in LDS (broadcast reads).
// ---------------------------------------------------------------------------
__global__ __launch_bounds__(256) void edge_scatter(
    const float* __restrict__ m, const float* __restrict__ basis_rad,
    const int* __restrict__ idx_atom, const float* __restrict__ W_rbf,
    float* __restrict__ acc, int nEdges)
{
  __shared__ __align__(16) float br[64 * 16];
  __shared__ int idx_s[64];
  const int tid = threadIdx.x;
  const int e0 = blockIdx.x * 64;
  const int ne = min(64, nEdges - e0);

  // this thread's two W_rbf columns (cols 2*tid, 2*tid+1), all 16 radial rows
  float2 wreg[16];
#pragma unroll
  for (int k = 0; k < 16; ++k)
    wreg[k] = *(const float2*)(W_rbf + k * 512 + 2 * tid);

  // stage basis tile: ne*16 floats, coalesced float4
  if (tid < ne * 4)
    ((float4*)br)[tid] = ((const float4*)(basis_rad + (size_t)e0 * 16))[tid];
  if (tid < ne) idx_s[tid] = idx_atom[e0 + tid];
  __syncthreads();

  for (int e = 0; e < ne; ++e) {
    const int atom = idx_s[e];
    float b0 = 0.f, b1 = 0.f;
#pragma unroll
    for (int k = 0; k < 16; ++k) {
      const float v = br[e * 16 + k];   // wave-uniform address -> broadcast
      b0 += v * wreg[k].x;
      b1 += v * wreg[k].y;
    }
    const float2 mv = *(const float2*)(m + (size_t)(e0 + e) * 512 + 2 * tid);
    float* dst = acc + (size_t)atom * 512 + 2 * tid;
    unsafeAtomicAdd(dst,     mv.x * b0);   // native global_atomic_add_f32
    unsafeAtomicAdd(dst + 1, mv.y * b1);
  }
}

// ---------------------------------------------------------------------------
// GEMM + silu (+ optional residual & scale):
//   p = A[M,K] @ W[K,256] ; s = silu(p)
//   out = res ? (res + s)*scale : s          (out is [M,256] f32)
// 64x64 tile, 4 waves (2x2), mfma_f32_16x16x32_bf16, fp32 inputs converted
// to bf16 during LDS staging. LDS rows padded to 40 shorts (80 B, 16B-aligned)
// to spread banks.
// ---------------------------------------------------------------------------
__global__ __launch_bounds__(256) void gemm_silu(
    const float* __restrict__ A, const float* __restrict__ W,
    const float* __restrict__ res, float* __restrict__ out,
    int M, int K, float scale)
{
  const int N = 256;
  __shared__ __align__(16) short As[64][40];  // [row][k]
  __shared__ __align__(16) short Bs[64][40];  // [col][k]  (W transposed)

  const int tid  = threadIdx.x;
  const int lane = tid & 63;
  const int wid  = tid >> 6;
  const int row0 = blockIdx.x * 64;
  const int col0 = blockIdx.y * 64;
  const int wr   = (wid >> 1) * 32;
  const int wc   = (wid & 1) * 32;
  const int llo  = lane & 15, lhi = lane >> 4;

  const int a_row = tid >> 2;         // 0..63
  const int a_kc  = (tid & 3) * 8;    // 0,8,16,24
  const int b_col = tid & 63;         // 0..63
  const int b_kb  = (tid >> 6) * 8;   // 0,8,16,24

  f32x4 acc[2][2] = {};

  for (int k0 = 0; k0 < K; k0 += 32) {
    // ---- stage A tile [64][32] as bf16 ----
    {
      short s8[8];
      const int gr = row0 + a_row;
      if (gr < M) {
        const float* p = A + (size_t)gr * K + k0 + a_kc;
        const float4 x0 = *(const float4*)p;
        const float4 x1 = *(const float4*)(p + 4);
        s8[0] = f2bf(x0.x); s8[1] = f2bf(x0.y); s8[2] = f2bf(x0.z); s8[3] = f2bf(x0.w);
        s8[4] = f2bf(x1.x); s8[5] = f2bf(x1.y); s8[6] = f2bf(x1.z); s8[7] = f2bf(x1.w);
      } else {
#pragma unroll
        for (int j = 0; j < 8; ++j) s8[j] = 0;
      }
      *(bf16x8*)&As[a_row][a_kc] = *(const bf16x8*)s8;
    }
    // ---- stage B tile transposed: Bs[col][k] = W[k0+k][col0+col] ----
    {
      short s8[8];
#pragma unroll
      for (int j = 0; j < 8; ++j)
        s8[j] = f2bf(W[(size_t)(k0 + b_kb + j) * N + col0 + b_col]);
      *(bf16x8*)&Bs[b_col][b_kb] = *(const bf16x8*)s8;
    }
    __syncthreads();

    bf16x8 af[2], bfr[2];
#pragma unroll
    for (int fr = 0; fr < 2; ++fr)
      af[fr] = *(const bf16x8*)&As[wr + fr * 16 + llo][lhi * 8];
#pragma unroll
    for (int fc = 0; fc < 2; ++fc)
      bfr[fc] = *(const bf16x8*)&Bs[wc + fc * 16 + llo][lhi * 8];
#pragma unroll
    for (int fr = 0; fr < 2; ++fr)
#pragma unroll
      for (int fc = 0; fc < 2; ++fc)
        acc[fr][fc] = __builtin_amdgcn_mfma_f32_16x16x32_bf16(
            af[fr], bfr[fc], acc[fr][fc], 0, 0, 0);
    __syncthreads();
  }

  // ---- epilogue: silu (+res, scale). C/D: col = lane&15, row = (lane>>4)*4+r
#pragma unroll
  for (int fr = 0; fr < 2; ++fr) {
#pragma unroll
    for (int fc = 0; fc < 2; ++fc) {
#pragma unroll
      for (int r = 0; r < 4; ++r) {
        const int grow = row0 + wr + fr * 16 + lhi * 4 + r;
        const int gcol = col0 + wc + fc * 16 + llo;
        if (grow < M) {
          const float p = acc[fr][fc][r];
          const float s = p / (1.f + __expf(-p));
          const size_t o = (size_t)grow * N + gcol;
          out[o] = res ? (res[o] + s) * scale : s;
        }
      }
    }
  }
}

// ---------------------------------------------------------------------------
extern "C" void kernel_launch(void* const* d_in, const int* in_sizes, int n_in,
                              void* d_out, int out_size, void* d_ws, size_t ws_size,
                              hipStream_t stream) {
  // inputs: 0 h (unused), 1 m, 2 basis_rad, 3 idx_atom, 4 W_rbf, 5 W_in,
  //         6 res_W1, 7 res_W2
  const float* m        = (const float*)d_in[1];
  const float* basis    = (const float*)d_in[2];
  const int*   idx_atom = (const int*)d_in[3];
  const float* W_rbf    = (const float*)d_in[4];
  const float* W_in     = (const float*)d_in[5];
  const float* W1       = (const float*)d_in[6];
  const float* W2       = (const float*)d_in[7];

  const int nAtoms = in_sizes[0] / 256;   // h is [A, 256]
  const int nEdges = in_sizes[3];         // idx_atom is [E]

  float* acc = (float*)d_ws;                                          // [A,512]
  float* t   = (float*)((char*)d_ws + (size_t)nAtoms * 512 * 4);      // [A,256]
  float* y   = (float*)d_out;                                         // [A,256]

  hipMemsetAsync(acc, 0, (size_t)nAtoms * 512 * sizeof(float), stream);

  const int eblocks = (nEdges + 63) / 64;
  edge_scatter<<<eblocks, 256, 0, stream>>>(m, basis, idx_atom, W_rbf, acc, nEdges);

  dim3 g((nAtoms + 63) / 64, 4);
  // x = silu(acc @ W_in)
  gemm_silu<<<g, 256, 0, stream>>>(acc, W_in, nullptr, y, nAtoms, 512, 1.0f);
  // residual layers
  for (int i = 0; i < 3; ++i) {
    gemm_silu<<<g, 256, 0, stream>>>(y, W1 + (size_t)i * 256 * 256, nullptr, t,
                                     nAtoms, 256, 1.0f);
    gemm_silu<<<g, 256, 0, stream>>>(t, W2 + (size_t)i * 256 * 256, y, y,
                                     nAtoms, 256, INV_SQRT_2F);
  }
}

// Round 4
// 888.870 us; speedup vs baseline: 1.7053x; 1.7053x over previous
//
#include <hip/hip_runtime.h>
#include <hip/hip_bf16.h>

typedef __attribute__((ext_vector_type(8))) short bf16x8;
typedef __attribute__((ext_vector_type(4))) float f32x4;
typedef __attribute__((ext_vector_type(2))) short short2v;

#define INV_SQRT_2F 0.70710678118654752440f

__device__ __forceinline__ short f2bf(float f) {
  union { float f; unsigned u; } v; v.f = f;
  unsigned r = v.u + 0x7fffu + ((v.u >> 16) & 1u);   // round-to-nearest-even
  return (short)(r >> 16);
}
__device__ __forceinline__ float bf2f(short s) {
  union { float f; unsigned u; } v;
  v.u = ((unsigned)(unsigned short)s) << 16;
  return v.f;
}

// ---------------------------------------------------------------------------
// CSR build: histogram -> scan -> scatter edge ids
// ---------------------------------------------------------------------------
__global__ __launch_bounds__(256) void hist_kernel(
    const int* __restrict__ idx, int* __restrict__ counts, int nEdges) {
  int e = blockIdx.x * 256 + threadIdx.x;
  if (e < nEdges) atomicAdd(&counts[idx[e]], 1);
}

__global__ __launch_bounds__(1024) void scan_offsets(
    const int* __restrict__ counts, int* __restrict__ offsets,
    int* __restrict__ heads, int nAtoms) {
  __shared__ int part[1024];
  const int tid = threadIdx.x;
  const int chunk = (nAtoms + 1023) >> 10;
  const int base = tid * chunk;
  int s = 0;
  for (int i = 0; i < chunk; ++i) {
    int a = base + i;
    if (a < nAtoms) s += counts[a];
  }
  part[tid] = s;
  __syncthreads();
  for (int off = 1; off < 1024; off <<= 1) {
    int v = (tid >= off) ? part[tid - off] : 0;
    __syncthreads();
    part[tid] += v;
    __syncthreads();
  }
  int excl = (tid == 0) ? 0 : part[tid - 1];
  for (int i = 0; i < chunk; ++i) {
    int a = base + i;
    if (a < nAtoms) {
      offsets[a] = excl;
      heads[a] = excl;
      excl += counts[a];
    }
  }
  if (tid == 1023) offsets[nAtoms] = part[1023];
}

__global__ __launch_bounds__(256) void scatter_ids(
    const int* __restrict__ idx, int* __restrict__ heads,
    int* __restrict__ order, int nEdges) {
  int e = blockIdx.x * 256 + threadIdx.x;
  if (e < nEdges) {
    int p = atomicAdd(&heads[idx[e]], 1);
    order[p] = e;
  }
}

// ---------------------------------------------------------------------------
// Weight pre-convert: f32 [K][N] -> bf16 transposed [N][K]
// Wt_in: 256x512 from W_in 512x256; Wt1/Wt2: 3x(256x256) transposed
// ---------------------------------------------------------------------------
__global__ __launch_bounds__(256) void convert_weights(
    const float* __restrict__ W_in, const float* __restrict__ W1,
    const float* __restrict__ W2, short* __restrict__ Wt_in,
    short* __restrict__ Wt1, short* __restrict__ Wt2) {
  int i = blockIdx.x * 256 + threadIdx.x;
  if (i < 131072) {                       // 256*512
    int n = i >> 9, k = i & 511;
    Wt_in[i] = f2bf(W_in[k * 256 + n]);
  } else if (i < 131072 + 196608) {       // 3*256*256
    int j = i - 131072;
    int l = j >> 16, r = j & 65535;
    int n = r >> 8, k = r & 255;
    Wt1[j] = f2bf(W1[l * 65536 + k * 256 + n]);
    Wt2[j] = f2bf(W2[l * 65536 + k * 256 + n]);
  }
}

// ---------------------------------------------------------------------------
// Gather-accumulate: one block per atom, 256 threads, 2 cols/thread.
// acc[atom][j] = sum_{e in atom} m[e][j] * (basis[e,:] . W_rbf[:,j])
// Output stored as bf16 (feeds bf16 GEMM; same rounding as before).
// ---------------------------------------------------------------------------
__global__ __launch_bounds__(256) void gather_edges(
    const float* __restrict__ m, const float* __restrict__ basis,
    const float* __restrict__ W_rbf, const int* __restrict__ order,
    const int* __restrict__ offsets, short* __restrict__ accb) {
  const int atom = blockIdx.x;
  const int tid = threadIdx.x;
  float2 w[16];
#pragma unroll
  for (int k = 0; k < 16; ++k)
    w[k] = *(const float2*)(W_rbf + k * 512 + 2 * tid);
  const int a0 = offsets[atom];
  const int a1 = offsets[atom + 1];
  float s0 = 0.f, s1 = 0.f;
  for (int i = a0; i < a1; ++i) {
    int eid = order[i];                       // uniform across block
    eid = __builtin_amdgcn_readfirstlane(eid);
    const float4* bp = (const float4*)(basis + (size_t)eid * 16);
    const float4 q0 = bp[0], q1 = bp[1], q2 = bp[2], q3 = bp[3];
    const float bb[16] = {q0.x, q0.y, q0.z, q0.w, q1.x, q1.y, q1.z, q1.w,
                          q2.x, q2.y, q2.z, q2.w, q3.x, q3.y, q3.z, q3.w};
    float b0 = 0.f, b1 = 0.f;
#pragma unroll
    for (int k = 0; k < 16; ++k) {
      b0 += bb[k] * w[k].x;
      b1 += bb[k] * w[k].y;
    }
    const float2 mv = *(const float2*)(m + (size_t)eid * 512 + 2 * tid);
    s0 += mv.x * b0;
    s1 += mv.y * b1;
  }
  short2v r;
  r.x = f2bf(s0);
  r.y = f2bf(s1);
  *(short2v*)(accb + (size_t)atom * 512 + 2 * tid) = r;
}

// ---------------------------------------------------------------------------
// GEMM + silu (+ optional residual & scale), all-bf16 inputs:
//   p = A[M,K](bf16) @ Wt[N=256,K](bf16, row=col of W) ; s = silu(p)
//   out = res ? (res + s)*scale : s      (bf16, or f32 for the final layer)
// 64x64 tile, BK=64, 4 waves (2x2), mfma_f32_16x16x32_bf16.
// ---------------------------------------------------------------------------
template <bool F32OUT>
__global__ __launch_bounds__(256) void gemm_silu_b(
    const short* __restrict__ A, const short* __restrict__ Wt,
    const short* __restrict__ res, void* __restrict__ outp,
    int M, int K, float scale) {
  __shared__ __align__(16) short As[64][72];
  __shared__ __align__(16) short Bs[64][72];
  const int tid = threadIdx.x, lane = tid & 63, wid = tid >> 6;
  const int row0 = blockIdx.x * 64, col0 = blockIdx.y * 64;
  const int wr = (wid >> 1) * 32, wc = (wid & 1) * 32;
  const int llo = lane & 15, lhi = lane >> 4;
  const int srow = tid >> 2, skc = (tid & 3) * 16;

  f32x4 acc[2][2] = {};

  for (int k0 = 0; k0 < K; k0 += 64) {
    // stage A [64 rows][64 k] bf16 (guarded rows -> zeros)
    bf16x8 a0v = {0, 0, 0, 0, 0, 0, 0, 0}, a1v = {0, 0, 0, 0, 0, 0, 0, 0};
    const int gr = row0 + srow;
    if (gr < M) {
      const short* p = A + (size_t)gr * K + k0 + skc;
      a0v = *(const bf16x8*)p;
      a1v = *(const bf16x8*)(p + 8);
    }
    *(bf16x8*)&As[srow][skc] = a0v;
    *(bf16x8*)&As[srow][skc + 8] = a1v;
    // stage B [64 cols][64 k] bf16 (N=256 always full)
    {
      const short* p = Wt + (size_t)(col0 + srow) * K + k0 + skc;
      *(bf16x8*)&Bs[srow][skc] = *(const bf16x8*)p;
      *(bf16x8*)&Bs[srow][skc + 8] = *(const bf16x8*)(p + 8);
    }
    __syncthreads();

    bf16x8 af[2][2], bfv[2][2];
#pragma unroll
    for (int ks = 0; ks < 2; ++ks) {
#pragma unroll
      for (int fr = 0; fr < 2; ++fr)
        af[ks][fr] = *(const bf16x8*)&As[wr + fr * 16 + llo][ks * 32 + lhi * 8];
#pragma unroll
      for (int fc = 0; fc < 2; ++fc)
        bfv[ks][fc] = *(const bf16x8*)&Bs[wc + fc * 16 + llo][ks * 32 + lhi * 8];
    }
#pragma unroll
    for (int ks = 0; ks < 2; ++ks)
#pragma unroll
      for (int fr = 0; fr < 2; ++fr)
#pragma unroll
        for (int fc = 0; fc < 2; ++fc)
          acc[fr][fc] = __builtin_amdgcn_mfma_f32_16x16x32_bf16(
              af[ks][fr], bfv[ks][fc], acc[fr][fc], 0, 0, 0);
    __syncthreads();
  }

  // epilogue: C/D mapping col = lane&15, row = (lane>>4)*4 + r
#pragma unroll
  for (int fr = 0; fr < 2; ++fr) {
#pragma unroll
    for (int fc = 0; fc < 2; ++fc) {
#pragma unroll
      for (int r = 0; r < 4; ++r) {
        const int grow = row0 + wr + fr * 16 + lhi * 4 + r;
        const int gcol = col0 + wc + fc * 16 + llo;
        if (grow < M) {
          const float p = acc[fr][fc][r];
          const float s = p / (1.f + __expf(-p));
          const size_t o = (size_t)grow * 256 + gcol;
          const float v = res ? (bf2f(res[o]) + s) * scale : s;
          if (F32OUT)
            ((float*)outp)[o] = v;
          else
            ((short*)outp)[o] = f2bf(v);
        }
      }
    }
  }
}

// ---------------------------------------------------------------------------
extern "C" void kernel_launch(void* const* d_in, const int* in_sizes, int n_in,
                              void* d_out, int out_size, void* d_ws, size_t ws_size,
                              hipStream_t stream) {
  // inputs: 0 h (unused), 1 m, 2 basis_rad, 3 idx_atom, 4 W_rbf, 5 W_in,
  //         6 res_W1, 7 res_W2
  const float* m     = (const float*)d_in[1];
  const float* basis = (const float*)d_in[2];
  const int* idx     = (const int*)d_in[3];
  const float* W_rbf = (const float*)d_in[4];
  const float* W_in  = (const float*)d_in[5];
  const float* W1    = (const float*)d_in[6];
  const float* W2    = (const float*)d_in[7];

  const int nAtoms = in_sizes[0] / 256;  // h is [A, 256]
  const int nEdges = in_sizes[3];        // idx_atom is [E]

  char* w = (char*)d_ws;
  short* accb  = (short*)w;             w += (size_t)nAtoms * 512 * 2;   // [A,512] bf16
  short* y     = (short*)w;             w += (size_t)nAtoms * 256 * 2;   // [A,256] bf16
  short* t     = (short*)w;             w += (size_t)nAtoms * 256 * 2;   // [A,256] bf16
  short* Wt_in = (short*)w;             w += (size_t)131072 * 2;         // [256,512] bf16
  short* Wt1   = (short*)w;             w += (size_t)196608 * 2;         // 3x[256,256]
  short* Wt2   = (short*)w;             w += (size_t)196608 * 2;
  int* counts  = (int*)w;               w += (size_t)nAtoms * 4;
  int* offsets = (int*)w;               w += (size_t)(nAtoms + 1) * 4;
  int* heads   = (int*)w;               w += (size_t)nAtoms * 4;
  int* order   = (int*)w;               w += (size_t)nEdges * 4;

  hipMemsetAsync(counts, 0, (size_t)nAtoms * 4, stream);

  const int eb = (nEdges + 255) / 256;
  hist_kernel<<<eb, 256, 0, stream>>>(idx, counts, nEdges);
  scan_offsets<<<1, 1024, 0, stream>>>(counts, offsets, heads, nAtoms);
  scatter_ids<<<eb, 256, 0, stream>>>(idx, heads, order, nEdges);
  convert_weights<<<2048, 256, 0, stream>>>(W_in, W1, W2, Wt_in, Wt1, Wt2);
  gather_edges<<<nAtoms, 256, 0, stream>>>(m, basis, W_rbf, order, offsets, accb);

  dim3 g((nAtoms + 63) / 64, 4);
  gemm_silu_b<false><<<g, 256, 0, stream>>>(accb, Wt_in, nullptr, y, nAtoms, 512, 1.0f);
  for (int i = 0; i < 3; ++i) {
    gemm_silu_b<false><<<g, 256, 0, stream>>>(y, Wt1 + (size_t)i * 65536, nullptr, t,
                                              nAtoms, 256, 1.0f);
    if (i == 2)
      gemm_silu_b<true><<<g, 256, 0, stream>>>(t, Wt2 + (size_t)i * 65536, y, d_out,
                                               nAtoms, 256, INV_SQRT_2F);
    else
      gemm_silu_b<false><<<g, 256, 0, stream>>>(t, Wt2 + (size_t)i * 65536, y, y,
                                                nAtoms, 256, INV_SQRT_2F);
  }
}